// Round 13
// baseline (575.886 us; speedup 1.0000x reference)
//
#include <hip/hip_runtime.h>
#include <hip/hip_fp16.h>
#include <cstdint>
#include <cstddef>

constexpr int NN  = 100000;
constexpr int EE  = 1600000;
constexpr int HID = 128;
constexpr int BUK = 256;                      // nodes per bucket (local id fits 8 bits)
constexpr int NBUK = (NN + BUK - 1) / BUK;    // 391 buckets
constexpr int BLKE = 2048;                    // edges per block in bucket passes
constexpr int NBE  = (EE + BLKE - 1) / BLKE;  // 782 edge blocks
constexpr int MH   = NBUK * NBE;              // 305762 flattened hist entries
constexpr int MH2  = 2 * MH;                  // concatenated dst|src histograms
constexpr int NSC  = (MH2 + 2047) / 2048;     // 299 scan chunks (<=512 for scan_top)

typedef float f32x4_t __attribute__((ext_vector_type(4)));
typedef short bf16x8_t __attribute__((ext_vector_type(8)));

static __device__ __forceinline__ short f2bf(float f) {
    union { float f; unsigned u; } x; x.f = f;
    unsigned r = x.u + 0x7FFF + ((x.u >> 16) & 1);   // RN-even
    return (short)(r >> 16);
}
static __device__ __forceinline__ float bf2f(short b) {
    union { unsigned u; float f; } x; x.u = ((unsigned)(unsigned short)b) << 16;
    return x.f;
}

// ---------------------------------------------------------------- pass 1: per-block bucket histograms, both sides (LDS atomics only)
__global__ __launch_bounds__(256) void bh_both_k(const int* __restrict__ src, const int* __restrict__ dst,
                                                 int* __restrict__ bh2) {
    __shared__ int hd[NBUK], hs[NBUK];
    int blk = blockIdx.x, t = threadIdx.x;
    for (int i = t; i < NBUK; i += 256) { hd[i] = 0; hs[i] = 0; }
    __syncthreads();
    int e0 = blk * BLKE, e1 = min(e0 + BLKE, EE);
    for (int e = e0 + t; e < e1; e += 256) {
        atomicAdd(&hd[dst[e] >> 8], 1);
        atomicAdd(&hs[src[e] >> 8], 1);
    }
    __syncthreads();
    for (int i = t; i < NBUK; i += 256) {
        bh2[i * NBE + blk]      = hd[i];
        bh2[MH + i * NBE + blk] = hs[i];
    }
}

// ---------------------------------------------------------------- 3-level exclusive scan over 2*MH (2048 elems/block)
__global__ __launch_bounds__(256) void scan_sum_k(const int* __restrict__ in, int* __restrict__ bsum, int n) {
    __shared__ int sc[256];
    int b = blockIdx.x, t = threadIdx.x;
    int base = b * 2048 + t * 8;
    int s = 0;
#pragma unroll
    for (int j = 0; j < 8; j++) { int idx = base + j; s += (idx < n) ? in[idx] : 0; }
    sc[t] = s; __syncthreads();
    for (int off = 128; off > 0; off >>= 1) {
        if (t < off) sc[t] += sc[t + off];
        __syncthreads();
    }
    if (t == 0) bsum[b] = sc[0];
}

__global__ __launch_bounds__(512) void scan_top_k(const int* __restrict__ bsum, int* __restrict__ boff, int nb) {
    __shared__ int sc[512];
    int t = threadIdx.x;
    int v = (t < nb) ? bsum[t] : 0;
    sc[t] = v; __syncthreads();
    for (int off = 1; off < 512; off <<= 1) {
        int u = (t >= off) ? sc[t - off] : 0;
        __syncthreads();
        sc[t] += u;
        __syncthreads();
    }
    if (t < nb) boff[t] = sc[t] - v;
}

__global__ __launch_bounds__(256) void scan_chunk_k(const int* __restrict__ in, const int* __restrict__ boff,
                                                    int* __restrict__ out, int n) {
    __shared__ int sc[256];
    int b = blockIdx.x, t = threadIdx.x;
    int base = b * 2048 + t * 8;
    int c[8];
    int s = 0;
#pragma unroll
    for (int j = 0; j < 8; j++) { int idx = base + j; c[j] = (idx < n) ? in[idx] : 0; s += c[j]; }
    sc[t] = s; __syncthreads();
    for (int off = 1; off < 256; off <<= 1) {
        int v = (t >= off) ? sc[t - off] : 0;
        __syncthreads();
        sc[t] += v;
        __syncthreads();
    }
    int excl = sc[t] - s + boff[b];
#pragma unroll
    for (int j = 0; j < 8; j++) {
        int idx = base + j;
        if (idx < n) out[idx] = excl;
        excl += c[j];
    }
}

// ---------------------------------------------------------------- pass 2: scatter into bucket order (LDS cursors)
__global__ __launch_bounds__(256) void scatter_both_k(const int* __restrict__ src, const int* __restrict__ dst,
                                                      const int* __restrict__ off2,
                                                      unsigned* __restrict__ pairs, unsigned char* __restrict__ sbyte) {
    __shared__ int cd[NBUK], cs[NBUK];
    int blk = blockIdx.x, t = threadIdx.x;
    for (int i = t; i < NBUK; i += 256) {
        cd[i] = off2[i * NBE + blk];
        cs[i] = off2[MH + i * NBE + blk] - EE;
    }
    __syncthreads();
    int e0 = blk * BLKE, e1 = min(e0 + BLKE, EE);
    for (int e = e0 + t; e < e1; e += 256) {
        int d = dst[e], s = src[e];
        int pd = atomicAdd(&cd[d >> 8], 1);
        pairs[pd] = ((unsigned)(d & 255) << 17) | (unsigned)s;
        int ps = atomicAdd(&cs[s >> 8], 1);
        sbyte[ps] = (unsigned char)(s & 255);
    }
}

// ---------------------------------------------------------------- per-bucket work, fused
__global__ __launch_bounds__(512) void bucket_csr_ocnt_k(
    const unsigned* __restrict__ pairs, const unsigned char* __restrict__ sbyte,
    const int* __restrict__ off2,
    int* __restrict__ rowptr, int* __restrict__ col,
    float* __restrict__ inorm, float* __restrict__ onorm) {
    __shared__ int hist[BUK];
    __shared__ int excl[BUK];
    __shared__ int psum[BUK];
    int t = threadIdx.x;

    if (blockIdx.x >= NBUK) {            // -------- out-degree counting
        int b = blockIdx.x - NBUK;
        int base = off2[MH + b * NBE] - EE;
        int endv = (b == NBUK - 1) ? EE : off2[MH + (b + 1) * NBE] - EE;
        if (t < BUK) hist[t] = 0;
        __syncthreads();
        for (int i = base + t; i < endv; i += 512) atomicAdd(&hist[sbyte[i]], 1);
        __syncthreads();
        if (t < BUK) {
            int node = b * BUK + t;
            if (node < NN) {
                int c = hist[t]; if (c < 1) c = 1;
                onorm[node] = rsqrtf((float)c);
            }
        }
        return;
    }

    int b = blockIdx.x;
    int base = off2[b * NBE];
    int endv = (b == NBUK - 1) ? EE : off2[(b + 1) * NBE];
    if (t < BUK) hist[t] = 0;
    __syncthreads();
    for (int i = base + t; i < endv; i += 512) atomicAdd(&hist[pairs[i] >> 17], 1);
    __syncthreads();
    int ps = 0;
    if (t < BUK) { ps = hist[t]; psum[t] = ps; }
    __syncthreads();
    for (int off = 1; off < BUK; off <<= 1) {
        int u = 0;
        if (t < BUK && t >= off) u = psum[t - off];
        __syncthreads();
        if (t < BUK) psum[t] += u;
        __syncthreads();
    }
    if (t < BUK) {
        int pex = psum[t] - ps;
        excl[t] = pex;
        int node = b * BUK + t;
        if (node < NN) {
            rowptr[node] = base + pex;
            int c = ps; if (c < 1) c = 1;
            inorm[node] = rsqrtf((float)c);
        }
    }
    if (b == NBUK - 1 && t == 0) rowptr[NN] = EE;
    __syncthreads();
    for (int i = base + t; i < endv; i += 512) {
        unsigned p = pairs[i];
        int pos = base + atomicAdd(&excl[p >> 17], 1);
        col[pos] = (int)(p & 0x1FFFFu);
    }
}

// ---------------------------------------------------------------- W12 = W1 @ W2 ; b12 = b1 @ W2 + b2 (merged)
__global__ __launch_bounds__(256) void w12_k(const float* __restrict__ W1, const float* __restrict__ W2,
                                             const float* __restrict__ b1, const float* __restrict__ b2,
                                             float* __restrict__ W12, float* __restrict__ b12) {
    if (blockIdx.x == 64) {
        int j = threadIdx.x;
        if (j < 128) {
            float acc = b2[j];
            for (int k = 0; k < 128; k++) acc = fmaf(b1[k], W2[k * 128 + j], acc);
            b12[j] = acc;
        }
        return;
    }
    int idx = blockIdx.x * 256 + threadIdx.x;   // 0..16383
    int i = idx >> 7, j = idx & 127;
    float a0 = 0.f, a1 = 0.f, a2 = 0.f, a3 = 0.f;
    for (int k = 0; k < 128; k += 4) {
        a0 = fmaf(W1[i * 128 + k],     W2[(k)     * 128 + j], a0);
        a1 = fmaf(W1[i * 128 + k + 1], W2[(k + 1) * 128 + j], a1);
        a2 = fmaf(W1[i * 128 + k + 2], W2[(k + 2) * 128 + j], a2);
        a3 = fmaf(W1[i * 128 + k + 3], W2[(k + 3) * 128 + j], a3);
    }
    W12[idx] = (a0 + a1) + (a2 + a3);
}

// ---------------------------------------------------------------- one-time weight staging to GLOBAL split planes (R13)
// Byte-identical sidx layout to R10's per-block LDS staging (NT=8 branch) —
// moved to a prep kernel so the GEMM carries no 64KB weight LDS (the 8
// waves/CU occupancy cap). 4 matrices: W12, Wg0, Wg1, Wg2. 256KB total,
// fully L2-resident during the GEMMs.
__global__ __launch_bounds__(256) void stage_w_k(const float* __restrict__ W12, const float* __restrict__ Wg,
                                                 short* __restrict__ wsp) {
    int mat = blockIdx.x;              // 0:W12, 1..3:Wg[l]
    const float* W = (mat == 0) ? W12 : (Wg + (size_t)(mat - 1) * 128 * 128);
    short* Bh = wsp + (size_t)mat * 2 * 16384;
    short* Bl = Bh + 16384;
    int t = threadIdx.x;
    for (int j = 0; j < 16; j++) {
        int fi = (j * 256 + t) * 4;
        int k = fi >> 7, n0 = fi & 127;
        float4 wv = *(const float4*)(W + fi);
        float wa[4] = {wv.x, wv.y, wv.z, wv.w};
#pragma unroll
        for (int cc = 0; cc < 4; cc++) {
            int g = n0 + cc;
            int q2 = g >> 2;
            int ntc = q2 & 7;                       // % 8
            int c = ((q2 >> 3) << 2) | (g & 3);     // (q2/8)*4 + (g&3)
            int kblk = k >> 5, ksub = k & 31;
            int lane_ = ((ksub >> 3) << 4) | c;
            int sidx = ((ntc * 4 + kblk) * 64 + lane_) * 8 + (ksub & 7);
            short hi = f2bf(wa[cc]);
            Bh[sidx] = hi; Bl[sidx] = f2bf(wa[cc] - bf2f(hi));
        }
    }
}

// ---------------------------------------------------------------- aggregation (fp16 gather, fp32 acc, split-bf16 out) — R10 verbatim
__global__ __launch_bounds__(256) void agg_k(const float4* __restrict__ h16, const int* __restrict__ rowptr,
                                             const int* __restrict__ col, const float* __restrict__ inorm,
                                             short* __restrict__ h0h, short* __restrict__ h0l) {
    int w = (int)((blockIdx.x * 256 + threadIdx.x) >> 6);
    if (w >= NN) return;
    int lane = threadIdx.x & 63;
    int q   = lane >> 4;
    int l16 = lane & 15;
    int beg = rowptr[w], end = rowptr[w + 1];
    float acc[8];
#pragma unroll
    for (int j = 0; j < 8; j++) acc[j] = 0.f;

    union HU { float4 f4; __half2 h2[4]; };
    int i = beg + q;
    for (; i + 12 < end; i += 16) {        // per quarter: edges i, i+4, i+8, i+12
        int s0 = col[i], s1 = col[i + 4], s2 = col[i + 8], s3 = col[i + 12];
        HU u0, u1, u2, u3;
        u0.f4 = h16[(size_t)s0 * 16 + l16];
        u1.f4 = h16[(size_t)s1 * 16 + l16];
        u2.f4 = h16[(size_t)s2 * 16 + l16];
        u3.f4 = h16[(size_t)s3 * 16 + l16];
#pragma unroll
        for (int p = 0; p < 4; p++) {
            float2 a = __half22float2(u0.h2[p]);
            float2 b = __half22float2(u1.h2[p]);
            float2 c = __half22float2(u2.h2[p]);
            float2 d = __half22float2(u3.h2[p]);
            acc[2 * p]     += (a.x + b.x) + (c.x + d.x);
            acc[2 * p + 1] += (a.y + b.y) + (c.y + d.y);
        }
    }
    for (; i < end; i += 4) {
        int s = col[i];
        HU u; u.f4 = h16[(size_t)s * 16 + l16];
#pragma unroll
        for (int p = 0; p < 4; p++) {
            float2 a = __half22float2(u.h2[p]);
            acc[2 * p]     += a.x;
            acc[2 * p + 1] += a.y;
        }
    }
#pragma unroll
    for (int mm = 16; mm <= 32; mm <<= 1)
#pragma unroll
        for (int j = 0; j < 8; j++) acc[j] += __shfl_xor(acc[j], mm);
    if (q == 0) {
        float s = inorm[w];
        bf16x8_t hv, lv;
#pragma unroll
        for (int j = 0; j < 8; j++) {
            float v = acc[j] * s;
            short hi = f2bf(v);
            hv[j] = hi;
            lv[j] = f2bf(v - bf2f(hi));
        }
        *(bf16x8_t*)&h0h[(size_t)w * 128 + l16 * 8] = hv;
        *(bf16x8_t*)&h0l[(size_t)w * 128 + l16 * 8] = lv;
    }
}

// ---------------------------------------------------------------- split-bf16 MFMA GEMM, GLOBAL weight planes (R13)
// R10's mfma_gemm_k (NT=8) with the LDS staging deleted: fragments read
// from the prep kernel's global planes at the IDENTICAL offsets. No weight
// LDS, no staging barrier -> occupancy VGPR/grid-limited. grid=1563 gives
// ~1 tile/wave, ~24 waves/CU (was 8). Tr transpose-store kept (16KB LDS).
template <bool RELU, bool OUTSCALE, bool OUTHALF, bool INSPLIT>
__global__ __launch_bounds__(256) void gw_gemm_k(
    const void* __restrict__ in, const short* __restrict__ inl,
    const short* __restrict__ gBh, const short* __restrict__ gBl,
    const float* __restrict__ bias,
    void* __restrict__ outp, const float* __restrict__ outscale,
    int nrows, int ncols, int ntiles) {

    __shared__ __half Tr[OUTHALF ? 4 * 16 * 128 : 1];   // per-wave 16x128 transpose tile

    const int t = threadIdx.x;
    const int wave = t >> 6;
    const int lane = t & 63;
    const int m    = lane & 15;     // node within tile
    const int kq   = lane >> 4;
    const int cbase = kq * 32;      // this thread's first output col (4*NT, NT=8)

    float bstat[32];
#pragma unroll
    for (int i = 0; i < 32; i++) {
        int g = cbase + i;
        bstat[i] = (g < ncols) ? bias[g] : 0.f;
    }

    const int wstride = gridDim.x * 4;
    for (int tile = blockIdx.x * 4 + wave; tile < ntiles; tile += wstride) {
        int row = tile * 16 + m;
        bool rv = row < nrows;

        bf16x8_t Ah[4], Al[4];
        if constexpr (INSPLIT) {
            const short* ih = (const short*)in + (size_t)row * 128 + kq * 8;
            const short* il = inl + (size_t)row * 128 + kq * 8;
#pragma unroll
            for (int kb = 0; kb < 4; kb++) {
                if (rv) {
                    Ah[kb] = *(const bf16x8_t*)(ih + kb * 32);
                    Al[kb] = *(const bf16x8_t*)(il + kb * 32);
                } else {
                    Ah[kb] = (bf16x8_t){0,0,0,0,0,0,0,0};
                    Al[kb] = (bf16x8_t){0,0,0,0,0,0,0,0};
                }
            }
        } else {
#pragma unroll
            for (int kb = 0; kb < 4; kb++) {
                const float* ap = (const float*)in + (size_t)row * 128 + kb * 32 + kq * 8;
                float4 p0, p1;
                if (rv) { p0 = *(const float4*)ap; p1 = *(const float4*)(ap + 4); }
                else    { p0 = make_float4(0,0,0,0); p1 = make_float4(0,0,0,0); }
                float av[8] = {p0.x, p0.y, p0.z, p0.w, p1.x, p1.y, p1.z, p1.w};
#pragma unroll
                for (int j = 0; j < 8; j++) {
                    float v = av[j];
                    short hi = f2bf(v);
                    Ah[kb][j] = hi;
                    Al[kb][j] = f2bf(v - bf2f(hi));
                }
            }
        }

        float osc = 1.f;
        if (OUTSCALE && rv) osc = outscale[row];

        float ov[32] __attribute__((aligned(16)));
#pragma unroll
        for (int nt = 0; nt < 8; nt++) {
            f32x4_t acc = {0.f, 0.f, 0.f, 0.f};
#pragma unroll
            for (int kb = 0; kb < 4; kb++) {
                const bf16x8_t bh = *(const bf16x8_t*)&gBh[((nt * 4 + kb) * 64 + lane) * 8];
                const bf16x8_t bl = *(const bf16x8_t*)&gBl[((nt * 4 + kb) * 64 + lane) * 8];
                acc = __builtin_amdgcn_mfma_f32_16x16x32_bf16(bh, Ah[kb], acc, 0, 0, 0);
                acc = __builtin_amdgcn_mfma_f32_16x16x32_bf16(bh, Al[kb], acc, 0, 0, 0);
                acc = __builtin_amdgcn_mfma_f32_16x16x32_bf16(bl, Ah[kb], acc, 0, 0, 0);
            }
#pragma unroll
            for (int r = 0; r < 4; r++) {
                float v = acc[r] + bstat[nt * 4 + r];
                if (RELU) v = fmaxf(v, 0.f);
                ov[nt * 4 + r] = v * osc;
            }
        }

        if constexpr (OUTHALF) {
            // coalesced store via per-wave LDS transpose (nrows % 16 == 0)
            __half* tw = &Tr[wave * 2048];
#pragma unroll
            for (int p = 0; p < 4; p++) {
                union { __half h[8]; float4 f4; } U;
#pragma unroll
                for (int j = 0; j < 8; j++) U.h[j] = __float2half_rn(ov[p * 8 + j]);
                int bo = (cbase * 2 + p * 16) ^ ((m & 7) << 4);   // XOR-swizzle within row
                *(float4*)((char*)(tw + m * 128) + bo) = U.f4;
            }
#pragma unroll
            for (int s2 = 0; s2 < 4; s2++) {
                int r = s2 * 4 + (lane >> 4);
                int bo = ((lane & 15) * 16) ^ ((r & 7) << 4);
                float4 v = *(const float4*)((char*)(tw + r * 128) + bo);
                *(float4*)((__half*)outp + (size_t)(tile * 16 + r) * ncols + (lane & 15) * 8) = v;
            }
        } else if (rv) {
            float4* p = (float4*)((float*)outp + (size_t)row * 128 + cbase);
#pragma unroll
            for (int j = 0; j < 8; j++) p[j] = ((const float4*)ov)[j];  // 128B contiguous/thread
        }
    }
}

// ---------------------------------------------------------------- classifier GEMM (R10 verbatim, NT=3, 12KB LDS)
template <int NT, bool RELU, bool OUTSCALE, bool OUTHALF, bool INSPLIT>
__global__ __launch_bounds__(256) void mfma_gemm_k(
    const void* __restrict__ in, const short* __restrict__ inl,
    const float* __restrict__ W, const float* __restrict__ bias,
    void* __restrict__ outp, const float* __restrict__ outscale,
    int nrows, int ncols, int ntiles) {

    __shared__ short Bh[NT * 2048];
    __shared__ short Bl[NT * 2048];

    const int t = threadIdx.x;

    for (int idx = t; idx < 128 * 64; idx += 256) {
        int k = idx >> 6, g = idx & 63;
        if (g < NT * 16) {
            float w = (g < 40) ? ((const float*)W)[k * 40 + g] : 0.f;
            int q2 = g >> 2;
            int ntc = q2 % NT;
            int c = (q2 / NT) * 4 + (g & 3);
            int kblk = k >> 5, ksub = k & 31;
            int lane_ = ((ksub >> 3) << 4) | c;
            int sidx = ((ntc * 4 + kblk) * 64 + lane_) * 8 + (ksub & 7);
            short hi = f2bf(w);
            Bh[sidx] = hi; Bl[sidx] = f2bf(w - bf2f(hi));
        }
    }
    __syncthreads();

    const int wave = t >> 6;
    const int lane = t & 63;
    const int m    = lane & 15;
    const int kq   = lane >> 4;
    const int cbase = kq * 4 * NT;

    float bstat[4 * NT];
#pragma unroll
    for (int i = 0; i < 4 * NT; i++) {
        int g = cbase + i;
        bstat[i] = (g < ncols) ? bias[g] : 0.f;
    }

    const int wstride = gridDim.x * 4;
    for (int tile = blockIdx.x * 4 + wave; tile < ntiles; tile += wstride) {
        int row = tile * 16 + m;
        bool rv = row < nrows;

        bf16x8_t Ah[4], Al[4];
#pragma unroll
        for (int kb = 0; kb < 4; kb++) {
            const float* ap = (const float*)in + (size_t)row * 128 + kb * 32 + kq * 8;
            float4 p0, p1;
            if (rv) { p0 = *(const float4*)ap; p1 = *(const float4*)(ap + 4); }
            else    { p0 = make_float4(0,0,0,0); p1 = make_float4(0,0,0,0); }
            float av[8] = {p0.x, p0.y, p0.z, p0.w, p1.x, p1.y, p1.z, p1.w};
#pragma unroll
            for (int j = 0; j < 8; j++) {
                float v = av[j];
                short hi = f2bf(v);
                Ah[kb][j] = hi;
                Al[kb][j] = f2bf(v - bf2f(hi));
            }
        }

        float ov[4 * NT] __attribute__((aligned(16)));
#pragma unroll
        for (int nt = 0; nt < NT; nt++) {
            f32x4_t acc = {0.f, 0.f, 0.f, 0.f};
#pragma unroll
            for (int kb = 0; kb < 4; kb++) {
                const bf16x8_t bh = *(const bf16x8_t*)&Bh[((nt * 4 + kb) * 64 + lane) * 8];
                const bf16x8_t bl = *(const bf16x8_t*)&Bl[((nt * 4 + kb) * 64 + lane) * 8];
                acc = __builtin_amdgcn_mfma_f32_16x16x32_bf16(bh, Ah[kb], acc, 0, 0, 0);
                acc = __builtin_amdgcn_mfma_f32_16x16x32_bf16(bh, Al[kb], acc, 0, 0, 0);
                acc = __builtin_amdgcn_mfma_f32_16x16x32_bf16(bl, Ah[kb], acc, 0, 0, 0);
            }
#pragma unroll
            for (int r = 0; r < 4; r++) ov[nt * 4 + r] = acc[r] + bstat[nt * 4 + r];
        }

        if (rv) {
            float* p = (float*)outp + (size_t)row * 40 + cbase;
#pragma unroll
            for (int j = 0; j < 3; j++) {
                if (cbase + j * 4 < 40) *(float4*)(p + j * 4) = ((const float4*)ov)[j];
            }
        }
    }
}

// ---------------------------------------------------------------- launch
extern "C" void kernel_launch(void* const* d_in, const int* in_sizes, int n_in,
                              void* d_out, int out_size, void* d_ws, size_t ws_size,
                              hipStream_t stream) {
    const float* x   = (const float*)d_in[0];
    const int*   src = (const int*)d_in[1];
    const int*   dst = (const int*)d_in[2];
    const float* W1  = (const float*)d_in[3];
    const float* b1  = (const float*)d_in[4];
    const float* W2  = (const float*)d_in[5];
    const float* b2  = (const float*)d_in[6];
    const float* Wg  = (const float*)d_in[7];   // [3][128][128]
    const float* bg  = (const float*)d_in[8];   // [3][128]
    const float* Wc  = (const float*)d_in[9];   // [128][40]
    const float* bc  = (const float*)d_in[10];  // [40]
    float* out = (float*)d_out;

    char* ws = (char*)d_ws;
    size_t off = 0;
    auto alloc = [&](size_t bytes) -> void* {
        void* p = ws + off;
        off += (bytes + 255) & ~(size_t)255;
        return p;
    };
    short*  h0h    = (short*)alloc((size_t)NN * HID * 2);    // agg out hi plane (bf16)
    short*  h0l    = (short*)alloc((size_t)NN * HID * 2);    // agg out lo plane (bf16)
    float*  h1     = (float*)alloc((size_t)NN * HID * 4);    // conv2 out (fp32)
    __half* h16    = (__half*)alloc((size_t)NN * HID * 2);   // agg in (fp16)
    float*  W12    = (float*)alloc(128 * 128 * 4);
    float*  b12    = (float*)alloc(128 * 4);
    short*  wsp    = (short*)alloc(4 * 2 * 16384 * 2);       // global split-weight planes (256KB)
    float*  onorm  = (float*)alloc((size_t)NN * 4);
    float*  inorm  = (float*)alloc((size_t)NN * 4);
    int*    rowptr = (int*)alloc((size_t)(NN + 1) * 4);
    int*    col    = (int*)alloc((size_t)EE * 4);
    int*    bh2    = (int*)alloc((size_t)MH2 * 4);
    int*    off2   = (int*)alloc((size_t)MH2 * 4);
    int*    bsum   = (int*)alloc((size_t)NSC * 4);
    int*    boff   = (int*)alloc((size_t)NSC * 4);
    // sort payloads alias h0h (consumed by bucket_csr_ocnt_k before agg writes)
    unsigned*      pairs = (unsigned*)h0h;                          // 6.4 MB
    unsigned char* sbyte = (unsigned char*)h0h + (size_t)EE * 4;    // 1.6 MB (within h0h)

    // ---- CSR build (no global atomics): single merged scan over dst|src
    bh_both_k<<<NBE, 256, 0, stream>>>(src, dst, bh2);
    scan_sum_k<<<NSC, 256, 0, stream>>>(bh2, bsum, MH2);
    scan_top_k<<<1, 512, 0, stream>>>(bsum, boff, NSC);
    scan_chunk_k<<<NSC, 256, 0, stream>>>(bh2, boff, off2, MH2);
    scatter_both_k<<<NBE, 256, 0, stream>>>(src, dst, off2, pairs, sbyte);
    bucket_csr_ocnt_k<<<2 * NBUK, 512, 0, stream>>>(pairs, sbyte, off2,
                                                    rowptr, col, inorm, onorm);

    // ---- weight fusion + global split-plane staging
    w12_k<<<65, 256, 0, stream>>>(W1, W2, b1, b2, W12, b12);
    stage_w_k<<<4, 256, 0, stream>>>(W12, Wg, wsp);

    const int ntiles = NN / 16;          // 6250 (exact)
    const int ggrid  = 1563;             // 6252 waves ~ 1 tile/wave, ~24 waves/CU

    const short* pW12h = wsp;                const short* pW12l = wsp + 16384;
    const short* pWg0h = wsp + 1 * 32768;    const short* pWg0l = pWg0h + 16384;
    const short* pWg1h = wsp + 2 * 32768;    const short* pWg1l = pWg1h + 16384;
    const short* pWg2h = wsp + 3 * 32768;    const short* pWg2l = pWg2h + 16384;

    // h16 = (x @ W12 + b12) * onorm           (fused feature1+feature2)
    gw_gemm_k<false, true, true, false><<<ggrid, 256, 0, stream>>>(
        x, nullptr, pW12h, pW12l, b12, h16, onorm, NN, 128, ntiles);
    for (int l = 0; l < 3; l++) {
        // (h0h,h0l) = split( inorm * sum_{src} h16[src] )
        agg_k<<<(NN * 64 + 255) / 256, 256, 0, stream>>>(
            (const float4*)h16, rowptr, col, inorm, h0h, h0l);
        const short* ph = (l == 0) ? pWg0h : (l == 1) ? pWg1h : pWg2h;
        const short* pl = (l == 0) ? pWg0l : (l == 1) ? pWg1l : pWg2l;
        if (l < 2) {
            // h16 = relu(h0 @ Wg + bg) * onorm   (fp16 out, feeds agg)
            gw_gemm_k<true, true, true, true><<<ggrid, 256, 0, stream>>>(
                h0h, h0l, ph, pl, bg + (size_t)l * 128, h16, onorm, NN, 128, ntiles);
        } else {
            // h1 = relu(h0 @ Wg + bg)            (fp32, feeds classifier)
            gw_gemm_k<true, false, false, true><<<ggrid, 256, 0, stream>>>(
                h0h, h0l, ph, pl, bg + (size_t)l * 128, h1, nullptr, NN, 128, ntiles);
        }
    }
    // out = h1 @ Wc + bc  (classifier, LDS weights, R10 verbatim)
    mfma_gemm_k<3, false, false, false, false><<<512, 256, 0, stream>>>(
        h1, nullptr, Wc, bc, out, nullptr, NN, 40, ntiles);
}

// Round 15
// 534.713 us; speedup vs baseline: 1.0770x; 1.0770x over previous
//
#include <hip/hip_runtime.h>
#include <hip/hip_fp16.h>
#include <cstdint>
#include <cstddef>

constexpr int NN  = 100000;
constexpr int EE  = 1600000;
constexpr int HID = 128;
constexpr int BUK = 256;                      // nodes per bucket (local id fits 8 bits)
constexpr int NBUK = (NN + BUK - 1) / BUK;    // 391 buckets
constexpr int BLKE = 2048;                    // edges per block in bucket passes
constexpr int NBE  = (EE + BLKE - 1) / BLKE;  // 782 edge blocks
constexpr int MH   = NBUK * NBE;              // 305762 flattened hist entries
constexpr int MH2  = 2 * MH;                  // concatenated dst|src histograms
constexpr int NSC  = (MH2 + 2047) / 2048;     // 299 scan chunks (<=512 for scan_top)

typedef float f32x4_t __attribute__((ext_vector_type(4)));
typedef short bf16x8_t __attribute__((ext_vector_type(8)));

static __device__ __forceinline__ short f2bf(float f) {
    union { float f; unsigned u; } x; x.f = f;
    unsigned r = x.u + 0x7FFF + ((x.u >> 16) & 1);   // RN-even
    return (short)(r >> 16);
}
static __device__ __forceinline__ float bf2f(short b) {
    union { unsigned u; float f; } x; x.u = ((unsigned)(unsigned short)b) << 16;
    return x.f;
}

// ---------------------------------------------------------------- pass 1: per-block bucket histograms, both sides (LDS atomics only)
__global__ __launch_bounds__(256) void bh_both_k(const int* __restrict__ src, const int* __restrict__ dst,
                                                 int* __restrict__ bh2) {
    __shared__ int hd[NBUK], hs[NBUK];
    int blk = blockIdx.x, t = threadIdx.x;
    for (int i = t; i < NBUK; i += 256) { hd[i] = 0; hs[i] = 0; }
    __syncthreads();
    int e0 = blk * BLKE, e1 = min(e0 + BLKE, EE);
    for (int e = e0 + t; e < e1; e += 256) {
        atomicAdd(&hd[dst[e] >> 8], 1);
        atomicAdd(&hs[src[e] >> 8], 1);
    }
    __syncthreads();
    for (int i = t; i < NBUK; i += 256) {
        bh2[i * NBE + blk]      = hd[i];
        bh2[MH + i * NBE + blk] = hs[i];
    }
}

// ---------------------------------------------------------------- 3-level exclusive scan over 2*MH (2048 elems/block)
__global__ __launch_bounds__(256) void scan_sum_k(const int* __restrict__ in, int* __restrict__ bsum, int n) {
    __shared__ int sc[256];
    int b = blockIdx.x, t = threadIdx.x;
    int base = b * 2048 + t * 8;
    int s = 0;
#pragma unroll
    for (int j = 0; j < 8; j++) { int idx = base + j; s += (idx < n) ? in[idx] : 0; }
    sc[t] = s; __syncthreads();
    for (int off = 128; off > 0; off >>= 1) {
        if (t < off) sc[t] += sc[t + off];
        __syncthreads();
    }
    if (t == 0) bsum[b] = sc[0];
}

__global__ __launch_bounds__(512) void scan_top_k(const int* __restrict__ bsum, int* __restrict__ boff, int nb) {
    __shared__ int sc[512];
    int t = threadIdx.x;
    int v = (t < nb) ? bsum[t] : 0;
    sc[t] = v; __syncthreads();
    for (int off = 1; off < 512; off <<= 1) {
        int u = (t >= off) ? sc[t - off] : 0;
        __syncthreads();
        sc[t] += u;
        __syncthreads();
    }
    if (t < nb) boff[t] = sc[t] - v;
}

__global__ __launch_bounds__(256) void scan_chunk_k(const int* __restrict__ in, const int* __restrict__ boff,
                                                    int* __restrict__ out, int n) {
    __shared__ int sc[256];
    int b = blockIdx.x, t = threadIdx.x;
    int base = b * 2048 + t * 8;
    int c[8];
    int s = 0;
#pragma unroll
    for (int j = 0; j < 8; j++) { int idx = base + j; c[j] = (idx < n) ? in[idx] : 0; s += c[j]; }
    sc[t] = s; __syncthreads();
    for (int off = 1; off < 256; off <<= 1) {
        int v = (t >= off) ? sc[t - off] : 0;
        __syncthreads();
        sc[t] += v;
        __syncthreads();
    }
    int excl = sc[t] - s + boff[b];
#pragma unroll
    for (int j = 0; j < 8; j++) {
        int idx = base + j;
        if (idx < n) out[idx] = excl;
        excl += c[j];
    }
}

// ---------------------------------------------------------------- pass 2: scatter into bucket order (LDS cursors)
__global__ __launch_bounds__(256) void scatter_both_k(const int* __restrict__ src, const int* __restrict__ dst,
                                                      const int* __restrict__ off2,
                                                      unsigned* __restrict__ pairs, unsigned char* __restrict__ sbyte) {
    __shared__ int cd[NBUK], cs[NBUK];
    int blk = blockIdx.x, t = threadIdx.x;
    for (int i = t; i < NBUK; i += 256) {
        cd[i] = off2[i * NBE + blk];
        cs[i] = off2[MH + i * NBE + blk] - EE;
    }
    __syncthreads();
    int e0 = blk * BLKE, e1 = min(e0 + BLKE, EE);
    for (int e = e0 + t; e < e1; e += 256) {
        int d = dst[e], s = src[e];
        int pd = atomicAdd(&cd[d >> 8], 1);
        pairs[pd] = ((unsigned)(d & 255) << 17) | (unsigned)s;
        int ps = atomicAdd(&cs[s >> 8], 1);
        sbyte[ps] = (unsigned char)(s & 255);
    }
}

// ---------------------------------------------------------------- per-bucket work, fused
__global__ __launch_bounds__(512) void bucket_csr_ocnt_k(
    const unsigned* __restrict__ pairs, const unsigned char* __restrict__ sbyte,
    const int* __restrict__ off2,
    int* __restrict__ rowptr, int* __restrict__ col,
    float* __restrict__ inorm, float* __restrict__ onorm) {
    __shared__ int hist[BUK];
    __shared__ int excl[BUK];
    __shared__ int psum[BUK];
    int t = threadIdx.x;

    if (blockIdx.x >= NBUK) {            // -------- out-degree counting
        int b = blockIdx.x - NBUK;
        int base = off2[MH + b * NBE] - EE;
        int endv = (b == NBUK - 1) ? EE : off2[MH + (b + 1) * NBE] - EE;
        if (t < BUK) hist[t] = 0;
        __syncthreads();
        for (int i = base + t; i < endv; i += 512) atomicAdd(&hist[sbyte[i]], 1);
        __syncthreads();
        if (t < BUK) {
            int node = b * BUK + t;
            if (node < NN) {
                int c = hist[t]; if (c < 1) c = 1;
                onorm[node] = rsqrtf((float)c);
            }
        }
        return;
    }

    int b = blockIdx.x;
    int base = off2[b * NBE];
    int endv = (b == NBUK - 1) ? EE : off2[(b + 1) * NBE];
    if (t < BUK) hist[t] = 0;
    __syncthreads();
    for (int i = base + t; i < endv; i += 512) atomicAdd(&hist[pairs[i] >> 17], 1);
    __syncthreads();
    int ps = 0;
    if (t < BUK) { ps = hist[t]; psum[t] = ps; }
    __syncthreads();
    for (int off = 1; off < BUK; off <<= 1) {
        int u = 0;
        if (t < BUK && t >= off) u = psum[t - off];
        __syncthreads();
        if (t < BUK) psum[t] += u;
        __syncthreads();
    }
    if (t < BUK) {
        int pex = psum[t] - ps;
        excl[t] = pex;
        int node = b * BUK + t;
        if (node < NN) {
            rowptr[node] = base + pex;
            int c = ps; if (c < 1) c = 1;
            inorm[node] = rsqrtf((float)c);
        }
    }
    if (b == NBUK - 1 && t == 0) rowptr[NN] = EE;
    __syncthreads();
    for (int i = base + t; i < endv; i += 512) {
        unsigned p = pairs[i];
        int pos = base + atomicAdd(&excl[p >> 17], 1);
        col[pos] = (int)(p & 0x1FFFFu);
    }
}

// ---------------------------------------------------------------- W12 = W1 @ W2 ; b12 = b1 @ W2 + b2; block 65: Wg2 split planes
__global__ __launch_bounds__(256) void w12_k(const float* __restrict__ W1, const float* __restrict__ W2,
                                             const float* __restrict__ b1, const float* __restrict__ b2,
                                             const float* __restrict__ Wg,
                                             float* __restrict__ W12, float* __restrict__ b12,
                                             short* __restrict__ wsp) {
    int t = threadIdx.x;
    if (blockIdx.x == 65) {
        // stage Wg2 to global split planes, sidx layout (R13 stage_w verbatim, NT=8)
        const float* W = Wg + 2 * 128 * 128;
        short* Bh = wsp;
        short* Bl = wsp + 16384;
        for (int j = 0; j < 16; j++) {
            int fi = (j * 256 + t) * 4;
            int k = fi >> 7, n0 = fi & 127;
            float4 wv = *(const float4*)(W + fi);
            float wa[4] = {wv.x, wv.y, wv.z, wv.w};
#pragma unroll
            for (int cc = 0; cc < 4; cc++) {
                int g = n0 + cc;
                int q2 = g >> 2;
                int ntc = q2 & 7;
                int c = ((q2 >> 3) << 2) | (g & 3);
                int kblk = k >> 5, ksub = k & 31;
                int lane_ = ((ksub >> 3) << 4) | c;
                int sidx = ((ntc * 4 + kblk) * 64 + lane_) * 8 + (ksub & 7);
                short hi = f2bf(wa[cc]);
                Bh[sidx] = hi; Bl[sidx] = f2bf(wa[cc] - bf2f(hi));
            }
        }
        return;
    }
    if (blockIdx.x == 64) {
        int j = t;
        if (j < 128) {
            float acc = b2[j];
            for (int k = 0; k < 128; k++) acc = fmaf(b1[k], W2[k * 128 + j], acc);
            b12[j] = acc;
        }
        return;
    }
    int idx = blockIdx.x * 256 + t;   // 0..16383
    int i = idx >> 7, j = idx & 127;
    float a0 = 0.f, a1 = 0.f, a2 = 0.f, a3 = 0.f;
    for (int k = 0; k < 128; k += 4) {
        a0 = fmaf(W1[i * 128 + k],     W2[(k)     * 128 + j], a0);
        a1 = fmaf(W1[i * 128 + k + 1], W2[(k + 1) * 128 + j], a1);
        a2 = fmaf(W1[i * 128 + k + 2], W2[(k + 2) * 128 + j], a2);
        a3 = fmaf(W1[i * 128 + k + 3], W2[(k + 3) * 128 + j], a3);
    }
    W12[idx] = (a0 + a1) + (a2 + a3);
}

// ---------------------------------------------------------------- aggregation (fp16 gather, fp32 acc, split-bf16 out) — R10 verbatim
__global__ __launch_bounds__(256) void agg_k(const float4* __restrict__ h16, const int* __restrict__ rowptr,
                                             const int* __restrict__ col, const float* __restrict__ inorm,
                                             short* __restrict__ h0h, short* __restrict__ h0l) {
    int w = (int)((blockIdx.x * 256 + threadIdx.x) >> 6);
    if (w >= NN) return;
    int lane = threadIdx.x & 63;
    int q   = lane >> 4;
    int l16 = lane & 15;
    int beg = rowptr[w], end = rowptr[w + 1];
    float acc[8];
#pragma unroll
    for (int j = 0; j < 8; j++) acc[j] = 0.f;

    union HU { float4 f4; __half2 h2[4]; };
    int i = beg + q;
    for (; i + 12 < end; i += 16) {        // per quarter: edges i, i+4, i+8, i+12
        int s0 = col[i], s1 = col[i + 4], s2 = col[i + 8], s3 = col[i + 12];
        HU u0, u1, u2, u3;
        u0.f4 = h16[(size_t)s0 * 16 + l16];
        u1.f4 = h16[(size_t)s1 * 16 + l16];
        u2.f4 = h16[(size_t)s2 * 16 + l16];
        u3.f4 = h16[(size_t)s3 * 16 + l16];
#pragma unroll
        for (int p = 0; p < 4; p++) {
            float2 a = __half22float2(u0.h2[p]);
            float2 b = __half22float2(u1.h2[p]);
            float2 c = __half22float2(u2.h2[p]);
            float2 d = __half22float2(u3.h2[p]);
            acc[2 * p]     += (a.x + b.x) + (c.x + d.x);
            acc[2 * p + 1] += (a.y + b.y) + (c.y + d.y);
        }
    }
    for (; i < end; i += 4) {
        int s = col[i];
        HU u; u.f4 = h16[(size_t)s * 16 + l16];
#pragma unroll
        for (int p = 0; p < 4; p++) {
            float2 a = __half22float2(u.h2[p]);
            acc[2 * p]     += a.x;
            acc[2 * p + 1] += a.y;
        }
    }
#pragma unroll
    for (int mm = 16; mm <= 32; mm <<= 1)
#pragma unroll
        for (int j = 0; j < 8; j++) acc[j] += __shfl_xor(acc[j], mm);
    if (q == 0) {
        float s = inorm[w];
        bf16x8_t hv, lv;
#pragma unroll
        for (int j = 0; j < 8; j++) {
            float v = acc[j] * s;
            short hi = f2bf(v);
            hv[j] = hi;
            lv[j] = f2bf(v - bf2f(hi));
        }
        *(bf16x8_t*)&h0h[(size_t)w * 128 + l16 * 8] = hv;
        *(bf16x8_t*)&h0l[(size_t)w * 128 + l16 * 8] = lv;
    }
}

// ---------------------------------------------------------------- split-bf16 MFMA GEMM (R10 verbatim: LDS weights, Tr transpose store)
template <int NT, bool RELU, bool OUTSCALE, bool OUTHALF, bool INSPLIT>
__global__ __launch_bounds__(256) void mfma_gemm_k(
    const void* __restrict__ in, const short* __restrict__ inl,
    const float* __restrict__ W, const float* __restrict__ bias,
    void* __restrict__ outp, const float* __restrict__ outscale,
    int nrows, int ncols, int ntiles) {

    __shared__ short Bh[NT * 2048];   // [ntc][kblk(4)][lane(64)][j(8)]
    __shared__ short Bl[NT * 2048];
    __shared__ __half Tr[OUTHALF ? 4 * 16 * 128 : 1];   // per-wave 16x128 transpose tile

    const int t = threadIdx.x;

    if constexpr (NT == 8) {
        for (int j = 0; j < 16; j++) {
            int fi = (j * 256 + t) * 4;
            int k = fi >> 7, n0 = fi & 127;
            float4 wv = *(const float4*)(W + fi);
            float wa[4] = {wv.x, wv.y, wv.z, wv.w};
#pragma unroll
            for (int cc = 0; cc < 4; cc++) {
                int g = n0 + cc;
                int q2 = g >> 2;
                int ntc = q2 & 7;
                int c = ((q2 >> 3) << 2) | (g & 3);
                int kblk = k >> 5, ksub = k & 31;
                int lane_ = ((ksub >> 3) << 4) | c;
                int sidx = ((ntc * 4 + kblk) * 64 + lane_) * 8 + (ksub & 7);
                short hi = f2bf(wa[cc]);
                Bh[sidx] = hi; Bl[sidx] = f2bf(wa[cc] - bf2f(hi));
            }
        }
    } else {
        for (int idx = t; idx < 128 * 64; idx += 256) {
            int k = idx >> 6, g = idx & 63;
            if (g < NT * 16) {
                float w = (g < 40) ? ((const float*)W)[k * 40 + g] : 0.f;
                int q2 = g >> 2;
                int ntc = q2 % NT;
                int c = (q2 / NT) * 4 + (g & 3);
                int kblk = k >> 5, ksub = k & 31;
                int lane_ = ((ksub >> 3) << 4) | c;
                int sidx = ((ntc * 4 + kblk) * 64 + lane_) * 8 + (ksub & 7);
                short hi = f2bf(w);
                Bh[sidx] = hi; Bl[sidx] = f2bf(w - bf2f(hi));
            }
        }
    }
    __syncthreads();   // Bh/Bl read-only below

    const int wave = t >> 6;
    const int lane = t & 63;
    const int m    = lane & 15;
    const int kq   = lane >> 4;
    const int cbase = kq * 4 * NT;

    float bstat[4 * NT];
#pragma unroll
    for (int i = 0; i < 4 * NT; i++) {
        int g = cbase + i;
        bstat[i] = (g < ncols) ? bias[g] : 0.f;
    }

    const int wstride = gridDim.x * 4;
    for (int tile = blockIdx.x * 4 + wave; tile < ntiles; tile += wstride) {
        int row = tile * 16 + m;
        bool rv = row < nrows;

        bf16x8_t Ah[4], Al[4];
        if constexpr (INSPLIT) {
            const short* ih = (const short*)in + (size_t)row * 128 + kq * 8;
            const short* il = inl + (size_t)row * 128 + kq * 8;
#pragma unroll
            for (int kb = 0; kb < 4; kb++) {
                if (rv) {
                    Ah[kb] = *(const bf16x8_t*)(ih + kb * 32);
                    Al[kb] = *(const bf16x8_t*)(il + kb * 32);
                } else {
                    Ah[kb] = (bf16x8_t){0,0,0,0,0,0,0,0};
                    Al[kb] = (bf16x8_t){0,0,0,0,0,0,0,0};
                }
            }
        } else {
#pragma unroll
            for (int kb = 0; kb < 4; kb++) {
                const float* ap = (const float*)in + (size_t)row * 128 + kb * 32 + kq * 8;
                float4 p0, p1;
                if (rv) { p0 = *(const float4*)ap; p1 = *(const float4*)(ap + 4); }
                else    { p0 = make_float4(0,0,0,0); p1 = make_float4(0,0,0,0); }
                float av[8] = {p0.x, p0.y, p0.z, p0.w, p1.x, p1.y, p1.z, p1.w};
#pragma unroll
                for (int j = 0; j < 8; j++) {
                    float v = av[j];
                    short hi = f2bf(v);
                    Ah[kb][j] = hi;
                    Al[kb][j] = f2bf(v - bf2f(hi));
                }
            }
        }

        float osc = 1.f;
        if (OUTSCALE && rv) osc = outscale[row];

        float ov[4 * NT] __attribute__((aligned(16)));
#pragma unroll
        for (int nt = 0; nt < NT; nt++) {
            f32x4_t acc = {0.f, 0.f, 0.f, 0.f};
#pragma unroll
            for (int kb = 0; kb < 4; kb++) {
                const bf16x8_t bh = *(const bf16x8_t*)&Bh[((nt * 4 + kb) * 64 + lane) * 8];
                const bf16x8_t bl = *(const bf16x8_t*)&Bl[((nt * 4 + kb) * 64 + lane) * 8];
                acc = __builtin_amdgcn_mfma_f32_16x16x32_bf16(bh, Ah[kb], acc, 0, 0, 0);
                acc = __builtin_amdgcn_mfma_f32_16x16x32_bf16(bh, Al[kb], acc, 0, 0, 0);
                acc = __builtin_amdgcn_mfma_f32_16x16x32_bf16(bl, Ah[kb], acc, 0, 0, 0);
            }
#pragma unroll
            for (int r = 0; r < 4; r++) {
                float v = acc[r] + bstat[nt * 4 + r];
                if (RELU) v = fmaxf(v, 0.f);
                ov[nt * 4 + r] = v * osc;
            }
        }

        if constexpr (OUTHALF) {
            __half* tw = &Tr[wave * 2048];
#pragma unroll
            for (int p = 0; p < 4; p++) {
                union { __half h[8]; float4 f4; } U;
#pragma unroll
                for (int j = 0; j < 8; j++) U.h[j] = __float2half_rn(ov[p * 8 + j]);
                int bo = (cbase * 2 + p * 16) ^ ((m & 7) << 4);
                *(float4*)((char*)(tw + m * 128) + bo) = U.f4;
            }
#pragma unroll
            for (int s2 = 0; s2 < 4; s2++) {
                int r = s2 * 4 + (lane >> 4);
                int bo = ((lane & 15) * 16) ^ ((r & 7) << 4);
                float4 v = *(const float4*)((char*)(tw + r * 128) + bo);
                *(float4*)((__half*)outp + (size_t)(tile * 16 + r) * ncols + (lane & 15) * 8) = v;
            }
        } else if (rv) {
            if constexpr (NT == 8) {
                float4* p = (float4*)((float*)outp + (size_t)row * 128 + cbase);
#pragma unroll
                for (int j = 0; j < 8; j++) p[j] = ((const float4*)ov)[j];
            } else {
                float* p = (float*)outp + (size_t)row * 40 + cbase;
#pragma unroll
                for (int j = 0; j < 3; j++) {
                    if (cbase + j * 4 < 40) *(float4*)(p + j * 4) = ((const float4*)ov)[j];
                }
            }
        }
    }
}

// ---------------------------------------------------------------- FUSED last conv + classifier (R14)
// conv half: R13 gw path (Wg2 from global split planes, A from h0 planes).
// bounce: per-wave 16x128 split-bf16 tile in LDS (wave-synchronous
// write->read, R10 Tr precedent; pad rows to 136 shorts for 2-way banks).
// classifier half: cls_gemm verbatim (Wc sidx staging, NT=3, fragment read
// addresses switched from global h1 to the bounce). Kills the 102MB h1
// round-trip + one dispatch. Numerically identical: bounce stores the
// same (hi, lo) split the classifier used to compute from fp32 h1.
__global__ __launch_bounds__(256) void conv_cls_k(
    const short* __restrict__ inh, const short* __restrict__ inl,
    const short* __restrict__ gBh, const short* __restrict__ gBl,
    const float* __restrict__ bg2,
    const float* __restrict__ Wc, const float* __restrict__ bc,
    float* __restrict__ out, int ntiles) {

    __shared__ short WcH[3 * 2048];          // 12KB
    __shared__ short WcL[3 * 2048];          // 12KB
    __shared__ short Lh[4][16][136];         // 17.4KB bounce hi (row pad: 2-way banks)
    __shared__ short Ll[4][16][136];         // 17.4KB bounce lo

    const int t = threadIdx.x;

    // Wc staging (cls_gemm NT=3 verbatim)
    for (int idx = t; idx < 128 * 64; idx += 256) {
        int k = idx >> 6, g = idx & 63;
        if (g < 48) {
            float w = (g < 40) ? Wc[k * 40 + g] : 0.f;
            int q2 = g >> 2;
            int ntc = q2 % 3;
            int c = (q2 / 3) * 4 + (g & 3);
            int kblk = k >> 5, ksub = k & 31;
            int lane_ = ((ksub >> 3) << 4) | c;
            int sidx = ((ntc * 4 + kblk) * 64 + lane_) * 8 + (ksub & 7);
            short hi = f2bf(w);
            WcH[sidx] = hi; WcL[sidx] = f2bf(w - bf2f(hi));
        }
    }
    __syncthreads();

    const int wave = t >> 6;
    const int lane = t & 63;
    const int m    = lane & 15;
    const int kq   = lane >> 4;
    const int cbase = kq * 32;      // conv output cols (NT=8 permutation)
    const int cbc   = kq * 12;      // classifier output cols (NT=3 permutation)

    float bstat[32];
#pragma unroll
    for (int i = 0; i < 32; i++) bstat[i] = bg2[cbase + i];
    float bstatC[12];
#pragma unroll
    for (int i = 0; i < 12; i++) {
        int g = cbc + i;
        bstatC[i] = (g < 40) ? bc[g] : 0.f;
    }

    const int wstride = gridDim.x * 4;
    for (int tile = blockIdx.x * 4 + wave; tile < ntiles; tile += wstride) {
        const int row = tile * 16 + m;          // always < NN (ntiles*16 == NN)

        // ---- conv A-fragments (INSPLIT, R10 verbatim)
        bf16x8_t Ah[4], Al[4];
        {
            const short* ih = inh + (size_t)row * 128 + kq * 8;
            const short* il = inl + (size_t)row * 128 + kq * 8;
#pragma unroll
            for (int kb = 0; kb < 4; kb++) {
                Ah[kb] = *(const bf16x8_t*)(ih + kb * 32);
                Al[kb] = *(const bf16x8_t*)(il + kb * 32);
            }
        }

        // ---- conv NT=8 with global weight planes (R13 gw verbatim)
        float ov[32] __attribute__((aligned(16)));
#pragma unroll
        for (int nt = 0; nt < 8; nt++) {
            f32x4_t acc = {0.f, 0.f, 0.f, 0.f};
#pragma unroll
            for (int kb = 0; kb < 4; kb++) {
                const bf16x8_t bh = *(const bf16x8_t*)&gBh[((nt * 4 + kb) * 64 + lane) * 8];
                const bf16x8_t bl = *(const bf16x8_t*)&gBl[((nt * 4 + kb) * 64 + lane) * 8];
                acc = __builtin_amdgcn_mfma_f32_16x16x32_bf16(bh, Ah[kb], acc, 0, 0, 0);
                acc = __builtin_amdgcn_mfma_f32_16x16x32_bf16(bh, Al[kb], acc, 0, 0, 0);
                acc = __builtin_amdgcn_mfma_f32_16x16x32_bf16(bl, Ah[kb], acc, 0, 0, 0);
            }
#pragma unroll
            for (int r = 0; r < 4; r++) {
                float v = acc[r] + bstat[nt * 4 + r];
                ov[nt * 4 + r] = fmaxf(v, 0.f);       // ReLU, no outscale (last layer)
            }
        }

        // ---- bounce: split-bf16 into per-wave LDS tile (wave-synchronous)
#pragma unroll
        for (int p = 0; p < 4; p++) {
            bf16x8_t hv, lv;
#pragma unroll
            for (int j = 0; j < 8; j++) {
                float v = ov[p * 8 + j];
                short hi = f2bf(v);
                hv[j] = hi;
                lv[j] = f2bf(v - bf2f(hi));
            }
            *(bf16x8_t*)&Lh[wave][m][cbase + p * 8] = hv;
            *(bf16x8_t*)&Ll[wave][m][cbase + p * 8] = lv;
        }
        // same-wave ds_write -> ds_read ordering via lgkmcnt (Tr precedent)

        // ---- classifier (cls_gemm compute, fragments from bounce)
        float ovc[12] __attribute__((aligned(16)));
#pragma unroll
        for (int ntc = 0; ntc < 3; ntc++) {
            f32x4_t acc = {0.f, 0.f, 0.f, 0.f};
#pragma unroll
            for (int kb = 0; kb < 4; kb++) {
                const bf16x8_t wh = *(const bf16x8_t*)&WcH[((ntc * 4 + kb) * 64 + lane) * 8];
                const bf16x8_t wl = *(const bf16x8_t*)&WcL[((ntc * 4 + kb) * 64 + lane) * 8];
                const bf16x8_t fh = *(const bf16x8_t*)&Lh[wave][m][kb * 32 + kq * 8];
                const bf16x8_t fl = *(const bf16x8_t*)&Ll[wave][m][kb * 32 + kq * 8];
                acc = __builtin_amdgcn_mfma_f32_16x16x32_bf16(wh, fh, acc, 0, 0, 0);
                acc = __builtin_amdgcn_mfma_f32_16x16x32_bf16(wh, fl, acc, 0, 0, 0);
                acc = __builtin_amdgcn_mfma_f32_16x16x32_bf16(wl, fh, acc, 0, 0, 0);
            }
#pragma unroll
            for (int r = 0; r < 4; r++) ovc[ntc * 4 + r] = acc[r] + bstatC[ntc * 4 + r];
        }

        // ---- store (cls_gemm verbatim)
        float* p = out + (size_t)row * 40 + cbc;
#pragma unroll
        for (int j = 0; j < 3; j++) {
            if (cbc + j * 4 < 40) *(float4*)(p + j * 4) = ((const float4*)ovc)[j];
        }
    }
}

// ---------------------------------------------------------------- launch
extern "C" void kernel_launch(void* const* d_in, const int* in_sizes, int n_in,
                              void* d_out, int out_size, void* d_ws, size_t ws_size,
                              hipStream_t stream) {
    const float* x   = (const float*)d_in[0];
    const int*   src = (const int*)d_in[1];
    const int*   dst = (const int*)d_in[2];
    const float* W1  = (const float*)d_in[3];
    const float* b1  = (const float*)d_in[4];
    const float* W2  = (const float*)d_in[5];
    const float* b2  = (const float*)d_in[6];
    const float* Wg  = (const float*)d_in[7];   // [3][128][128]
    const float* bg  = (const float*)d_in[8];   // [3][128]
    const float* Wc  = (const float*)d_in[9];   // [128][40]
    const float* bc  = (const float*)d_in[10];  // [40]
    float* out = (float*)d_out;

    char* ws = (char*)d_ws;
    size_t off = 0;
    auto alloc = [&](size_t bytes) -> void* {
        void* p = ws + off;
        off += (bytes + 255) & ~(size_t)255;
        return p;
    };
    short*  h0h    = (short*)alloc((size_t)NN * HID * 2);    // agg out hi plane (bf16)
    short*  h0l    = (short*)alloc((size_t)NN * HID * 2);    // agg out lo plane (bf16)
    __half* h16    = (__half*)alloc((size_t)NN * HID * 2);   // agg in (fp16)
    float*  W12    = (float*)alloc(128 * 128 * 4);
    float*  b12    = (float*)alloc(128 * 4);
    short*  wsp    = (short*)alloc(2 * 16384 * 2);           // Wg2 global split planes (64KB)
    float*  onorm  = (float*)alloc((size_t)NN * 4);
    float*  inorm  = (float*)alloc((size_t)NN * 4);
    int*    rowptr = (int*)alloc((size_t)(NN + 1) * 4);
    int*    col    = (int*)alloc((size_t)EE * 4);
    int*    bh2    = (int*)alloc((size_t)MH2 * 4);
    int*    off2   = (int*)alloc((size_t)MH2 * 4);
    int*    bsum   = (int*)alloc((size_t)NSC * 4);
    int*    boff   = (int*)alloc((size_t)NSC * 4);
    // sort payloads alias h0h (consumed by bucket_csr_ocnt_k before agg writes)
    unsigned*      pairs = (unsigned*)h0h;                          // 6.4 MB
    unsigned char* sbyte = (unsigned char*)h0h + (size_t)EE * 4;    // 1.6 MB (within h0h)

    // ---- CSR build (no global atomics): single merged scan over dst|src
    bh_both_k<<<NBE, 256, 0, stream>>>(src, dst, bh2);
    scan_sum_k<<<NSC, 256, 0, stream>>>(bh2, bsum, MH2);
    scan_top_k<<<1, 512, 0, stream>>>(bsum, boff, NSC);
    scan_chunk_k<<<NSC, 256, 0, stream>>>(bh2, boff, off2, MH2);
    scatter_both_k<<<NBE, 256, 0, stream>>>(src, dst, off2, pairs, sbyte);
    bucket_csr_ocnt_k<<<2 * NBUK, 512, 0, stream>>>(pairs, sbyte, off2,
                                                    rowptr, col, inorm, onorm);

    // ---- weight fusion + Wg2 plane staging (blocks 0..63: W12; 64: b12; 65: Wg2 planes)
    w12_k<<<66, 256, 0, stream>>>(W1, W2, b1, b2, Wg, W12, b12, wsp);

    const int ntiles = NN / 16;          // 6250 (exact)
    const int ggrid  = 512;

    // h16 = (x @ W12 + b12) * onorm           (fused feature1+feature2)
    mfma_gemm_k<8, false, true, true, false><<<ggrid, 256, 0, stream>>>(
        x, nullptr, W12, b12, h16, onorm, NN, 128, ntiles);
    for (int l = 0; l < 3; l++) {
        // (h0h,h0l) = split( inorm * sum_{src} h16[src] )
        agg_k<<<(NN * 64 + 255) / 256, 256, 0, stream>>>(
            (const float4*)h16, rowptr, col, inorm, h0h, h0l);
        if (l < 2) {
            // h16 = relu(h0 @ Wg + bg) * onorm   (fp16 out, feeds agg)
            mfma_gemm_k<8, true, true, true, true><<<ggrid, 256, 0, stream>>>(
                h0h, h0l, Wg + (size_t)l * 128 * 128, bg + (size_t)l * 128, h16, onorm, NN, 128, ntiles);
        } else {
            // out = relu(h0 @ Wg2 + bg2) @ Wc + bc   (fused last conv + classifier)
            conv_cls_k<<<ggrid, 256, 0, stream>>>(
                h0h, h0l, wsp, wsp + 16384, bg + 2 * 128, Wc, bc, out, ntiles);
        }
    }
}